// Round 7
// baseline (583.659 us; speedup 1.0000x reference)
//
#include <hip/hip_runtime.h>
#include <hip/hip_bf16.h>
#include <math.h>

#define BATCH 8
#define KK 19
#define CC 512
#define HW 16384
#define HW4 (HW/4)          // 4096 float4 per row
#define NSPLIT 4
#define ITERS (HW4/(NSPLIT*64))   // 16 iterations of 64 float4 positions

// ---------------- Kernel 0: zero d_out (replaces hipMemsetAsync; graph-safe) ----
// out has 8*512*19 = 77824 floats = 19456 float4 = 76 WGs x 256 thr.
__global__ __launch_bounds__(256) void zero_out(float4* __restrict__ out) {
    out[blockIdx.x * 256 + threadIdx.x] = make_float4(0.f, 0.f, 0.f, 0.f);
}

// ---------------- Kernel 1: row softmax (two-pass online, low VGPR) ----------------
// One WG (256 thr) per (b,k) row of 16384 floats. Pass 1: online (m,s).
// Pass 2: reload (L2-warm) and store normalized. ~15 live regs, no spill.
__global__ __launch_bounds__(256) void softmax_rows(const float* __restrict__ probs,
                                                    float* __restrict__ attn) {
    const int row = blockIdx.x;                       // 0..151  (= b*19 + k)
    const float4* p = (const float4*)(probs + (size_t)row * HW);
    float4* a = (float4*)(attn + (size_t)row * HW);
    const int t = threadIdx.x;

    float m = -INFINITY, s = 0.f;
#pragma unroll 4
    for (int i = 0; i < 16; ++i) {
        float4 v = p[i * 256 + t];
        float mx = fmaxf(fmaxf(v.x, v.y), fmaxf(v.z, v.w));
        float mn = fmaxf(m, mx);
        s = s * __expf(m - mn)
          + __expf(v.x - mn) + __expf(v.y - mn) + __expf(v.z - mn) + __expf(v.w - mn);
        m = mn;
    }
    // wave-level (m,s) merge
#pragma unroll
    for (int off = 32; off; off >>= 1) {
        float mo = __shfl_xor(m, off);
        float so = __shfl_xor(s, off);
        float mn = fmaxf(m, mo);
        s = s * __expf(m - mn) + so * __expf(mo - mn);
        m = mn;
    }
    __shared__ float sm[4], ss[4];
    if ((t & 63) == 0) { sm[t >> 6] = m; ss[t >> 6] = s; }
    __syncthreads();
    const float M = fmaxf(fmaxf(sm[0], sm[1]), fmaxf(sm[2], sm[3]));
    const float S = ss[0] * __expf(sm[0] - M) + ss[1] * __expf(sm[1] - M)
                  + ss[2] * __expf(sm[2] - M) + ss[3] * __expf(sm[3] - M);
    const float inv = 1.0f / S;

#pragma unroll 4
    for (int i = 0; i < 16; ++i) {
        float4 v = p[i * 256 + t];
        float4 o;
        o.x = __expf(v.x - M) * inv;
        o.y = __expf(v.y - M) * inv;
        o.z = __expf(v.z - M) * inv;
        o.w = __expf(v.w - M) * inv;
        a[i * 256 + t] = o;
    }
}

// ---------------- Kernel 2: ctx[k,c] = sum_n attn[k,n] * feats[c,n] ----------------
// Grid (C/16=32, B=8, NSPLIT=4) = 1024 blocks, 4/CU (LDS-limited), 16 waves/CU.
// Block covers 16 c-rows (wave w -> c0+4w..+3) and one n-quarter.
// attn tile [19][64 float4] double-buffered in LDS, staged with
// global_load_lds width=16 (linear LDS dest = wave-uniform base + lane*16;
// per-wave row j*4+w, 64 consecutive float4s -> 1KB coalesced per instr).
// No staging VGPRs -> acc[19][4] fits the 128-VGPR budget from
// amdgpu_waves_per_eu(4,4)  (round-3 bug: 64-VGPR alloc spilled acc).
// The compiler's vmcnt(0) drain before s_barrier makes the 2-phase
// double-buffer correct without explicit waits.
__global__ __launch_bounds__(256) __attribute__((amdgpu_waves_per_eu(4, 4)))
void ctx_kernel(const float* __restrict__ feats,
                const float* __restrict__ attn,
                float* __restrict__ out) {
    const int cblk = blockIdx.x;          // 0..31
    const int b    = blockIdx.y;          // 0..7
    const int ns   = blockIdx.z;          // 0..3  (n-quarter)
    const int t    = threadIdx.x;
    const int wave = t >> 6;
    const int lane = t & 63;
    const int c0   = cblk * 16 + wave * 4;

    __shared__ float4 abuf[2][KK][64];    // 38912 B

    const float4* af = (const float4*)attn  + (size_t)b * KK * HW4;
    const float4* ff = (const float4*)feats + ((size_t)b * CC + c0) * HW4;

    const int nbase0 = ns * ITERS * 64;

    // stage rows j*4+wave of the attn tile at column block nb into abuf[buf]
    #define STAGE(buf, nb)                                                      \
        do {                                                                    \
            _Pragma("unroll")                                                   \
            for (int j = 0; j < 5; ++j) {                                       \
                const int row = j * 4 + wave;                                   \
                if (row < KK) {                                                 \
                    const float4* src = af + (size_t)row * HW4 + (nb) + lane;   \
                    __builtin_amdgcn_global_load_lds(                           \
                        (const __attribute__((address_space(1))) void*)src,     \
                        (__attribute__((address_space(3))) void*)&abuf[buf][row][0], \
                        16, 0, 0);                                              \
                }                                                               \
            }                                                                   \
        } while (0)

    // ---- prologue: stage tile 0 ----
    STAGE(0, nbase0);
    __syncthreads();

    float acc[KK][4];
#pragma unroll
    for (int k = 0; k < KK; ++k)
#pragma unroll
        for (int ci = 0; ci < 4; ++ci) acc[k][ci] = 0.f;

    int cur = 0;
#pragma unroll 1
    for (int it = 0; it < ITERS; ++it) {
        // issue next tile's loads into the other buffer (in flight across compute)
        if (it + 1 < ITERS) {
            if (cur == 0) STAGE(1, nbase0 + (it + 1) * 64);
            else          STAGE(0, nbase0 + (it + 1) * 64);
        }
        // compute on abuf[cur]
        const int nq = nbase0 + it * 64 + lane;
        float4 fv[4];
#pragma unroll
        for (int ci = 0; ci < 4; ++ci) fv[ci] = ff[(size_t)ci * HW4 + nq];
#pragma unroll
        for (int k = 0; k < KK; ++k) {
            const float4 av = abuf[cur][k][lane];
#pragma unroll
            for (int ci = 0; ci < 4; ++ci) {
                acc[k][ci] += av.x * fv[ci].x + av.y * fv[ci].y
                            + av.z * fv[ci].z + av.w * fv[ci].w;
            }
        }
        __syncthreads();   // drains vmcnt -> next buffer ready
        cur ^= 1;
    }
    #undef STAGE

    // wave butterfly: sum over the 64 n-positions (lanes)
#pragma unroll
    for (int k = 0; k < KK; ++k) {
#pragma unroll
        for (int ci = 0; ci < 4; ++ci) {
            float s = acc[k][ci];
#pragma unroll
            for (int off = 32; off; off >>= 1) s += __shfl_xor(s, off);
            acc[k][ci] = s;
        }
    }

    // lane 0 of each wave owns distinct c's -> compile-time-indexed atomicAdds
    if (lane == 0) {
#pragma unroll
        for (int k = 0; k < KK; ++k)
#pragma unroll
            for (int ci = 0; ci < 4; ++ci)
                atomicAdd(&out[((size_t)b * CC + (c0 + ci)) * KK + k], acc[k][ci]);
    }
}

extern "C" void kernel_launch(void* const* d_in, const int* in_sizes, int n_in,
                              void* d_out, int out_size, void* d_ws, size_t ws_size,
                              hipStream_t stream) {
    const float* feats = (const float*)d_in[0];
    const float* probs = (const float*)d_in[1];
    float* out = (float*)d_out;
    float* attn = (float*)d_ws;   // 8*19*16384 floats = ~9.5 MB scratch

    zero_out<<<(CC * KK * BATCH) / (256 * 4), 256, 0, stream>>>((float4*)out);
    softmax_rows<<<BATCH * KK, 256, 0, stream>>>(probs, attn);
    ctx_kernel<<<dim3(CC / 16, BATCH, NSPLIT), 256, 0, stream>>>(feats, attn, out);
}